// Round 5
// baseline (1522.543 us; speedup 1.0000x reference)
//
#include <hip/hip_runtime.h>
#include <hip/hip_bf16.h>

// VectorQuantizer on MI355X (gfx950). Inputs fp32, output buffer fp32.
// z: [64,256,32,32] f32; E: [1024,256] f32.
// out (f32): z_q[16777216] | loss[1] | indices[65536] (float(idx), bf16-roundtrip)
//
// R11: zero-LDS gemm. R10 post-mortem: gemm 94% stalled at 2 waves/SIMD;
// limiter = 64KB LDS Z-slab + 192 VGPR. The slab only fed (a) A-frag bf16
// packing -> precompute fragment-ordered Zbf globally (new convert_z, reusing
// R9 staging + R10 af-pack verbatim), and (b) exact-eval z reads -> R8's
// validated strided-global path. gemm: A = 8 coalesced dwordx4, B = validated
// dbl-buffered L2 stream, no LDS, no barriers, launch_bounds(256,4) (<=128
// VGPR -> 4 waves/SIMD). Eval = R8's np-exact inline (a8 pairwise + seq FMA,
// c ascending) + R10's float4-er pipeline. All score/eval bit patterns match
// R6..R10 -> margin/ballot/refine machinery verbatim.
//
// out layout during pipeline: Zbf (frag-ordered bf16 Z, 32MB) at out[0];
// Ebf (frag-ordered bf16 E, 512KB) at out+32MB; both consumed by gemm,
// overwritten by gather_loss afterwards.
// ws: [0,4) loss f32 | [4,8) full cnt | [64,4160) Se[1024] | [4352,+32K) full list

typedef __attribute__((ext_vector_type(8))) short short8;
typedef __attribute__((ext_vector_type(4))) float floatx4;

#define MARGIN 2.5e-4f
#define FULL_CAP 8192u
#define IDX_OFF 16777217

__device__ __forceinline__ unsigned short f2b(float f) {
    union { float f; unsigned int i; } x; x.f = f;
    unsigned int i = x.i;
    unsigned int r = (i + 0x7fffu + ((i >> 16) & 1u)) >> 16;  // RN-even
    return (unsigned short)r;
}
__device__ __forceinline__ float b2f(unsigned short u) {
    union { unsigned int i; float f; } x; x.i = ((unsigned int)u) << 16; return x.f;
}
__device__ __forceinline__ unsigned int bf2bits(__hip_bfloat162 h) {
    union { __hip_bfloat162 h; unsigned int u; } x; x.h = h; return x.u;
}

// numpy pairwise sum of squares, n=256 contiguous: 128+128, each with 8
// stride-8 accumulators, combine ((r0+r1)+(r2+r3))+((r4+r5)+(r6+r7)).
__device__ __forceinline__ float np_pairwise_sumsq(const float* __restrict__ a) {
    float blk[2];
    #pragma unroll
    for (int h = 0; h < 2; h++) {
        const float* p = a + h * 128;
        float r0 = __fmul_rn(p[0], p[0]), r1 = __fmul_rn(p[1], p[1]);
        float r2 = __fmul_rn(p[2], p[2]), r3 = __fmul_rn(p[3], p[3]);
        float r4 = __fmul_rn(p[4], p[4]), r5 = __fmul_rn(p[5], p[5]);
        float r6 = __fmul_rn(p[6], p[6]), r7 = __fmul_rn(p[7], p[7]);
        for (int i = 8; i < 128; i += 8) {
            r0 = __fadd_rn(r0, __fmul_rn(p[i + 0], p[i + 0]));
            r1 = __fadd_rn(r1, __fmul_rn(p[i + 1], p[i + 1]));
            r2 = __fadd_rn(r2, __fmul_rn(p[i + 2], p[i + 2]));
            r3 = __fadd_rn(r3, __fmul_rn(p[i + 3], p[i + 3]));
            r4 = __fadd_rn(r4, __fmul_rn(p[i + 4], p[i + 4]));
            r5 = __fadd_rn(r5, __fmul_rn(p[i + 5], p[i + 5]));
            r6 = __fadd_rn(r6, __fmul_rn(p[i + 6], p[i + 6]));
            r7 = __fadd_rn(r7, __fmul_rn(p[i + 7], p[i + 7]));
        }
        blk[h] = __fadd_rn(__fadd_rn(__fadd_rn(r0, r1), __fadd_rn(r2, r3)),
                           __fadd_rn(__fadd_rn(r4, r5), __fadd_rn(r6, r7)));
    }
    return __fadd_rn(blk[0], blk[1]);
}

// ---------------- kernel 1a: E f32 -> bf16 fragment order, + Se ----------------
// Element (n,k) -> group g = ((nt*4+nf)*8+ks)*4+hi, slot lo*8+j (validated
// R7/R8). Blocks 0-3 additionally compute Se[k] np-exact.
__global__ __launch_bounds__(256) void convert_e(const float* __restrict__ E,
                                                 unsigned short* __restrict__ Ebf,
                                                 float* __restrict__ Se) {
    int t = blockIdx.x * 256 + threadIdx.x;
    int n = t >> 5;
    int oct = t & 31;                 // k-octet: k = oct*8 + j ; ks=oct>>2, hi=oct&3
    int nt = n >> 6, nf = (n >> 4) & 3, lo = n & 15;
    int g = ((nt * 4 + nf) * 8 + (oct >> 2)) * 4 + (oct & 3);
    const float* src = E + n * 256 + oct * 8;
    union { short8 s; unsigned int d[4]; } u;
    #pragma unroll
    for (int j = 0; j < 4; j++)
        u.d[j] = bf2bits(__float22bfloat162_rn(make_float2(src[2 * j], src[2 * j + 1])));
    *(short8*)(Ebf + g * 128 + lo * 8) = u.s;
    if (blockIdx.x < 4) {
        int k = blockIdx.x * 256 + threadIdx.x;
        Se[k] = np_pairwise_sumsq(E + k * 256);
    }
}

// ---------------- kernel 1b: Z f32 -> bf16 A-fragment order ----------------
// 1024 blocks x 64 rows. Stage slab (R9-validated pattern) -> pack A-frags
// (R10-validated code) -> store fragment (G,ks) = 1KB at (G*8+ks)*1024 bytes,
// lane slice +l*16, where G = row/16 = blockIdx*4 + w.
__global__ __launch_bounds__(256) void convert_z(const float* __restrict__ Z,
                                                 unsigned short* __restrict__ Zbf) {
    __shared__ __align__(16) float Zl[16384];   // [c][x]: c*64 + x
    const int t  = threadIdx.x;
    const int w  = t >> 6;
    const int l  = t & 63;
    const int lo = l & 15;
    const int hi = l >> 4;
    const int m0 = blockIdx.x * 64;
    const int b  = m0 >> 10;
    const int hwb = m0 & 1023;
    const float* Zb = Z + (size_t)b * 262144;

    #pragma unroll
    for (int j = 0; j < 16; j++) {
        int iw = w + j * 4;
        __builtin_amdgcn_global_load_lds(
            (const __attribute__((address_space(1))) unsigned int*)
                (Zb + (iw * 4 + hi) * 1024 + hwb + lo * 4),
            (__attribute__((address_space(3))) unsigned int*)((char*)Zl + iw * 1024),
            16, 0, 0);
    }
    asm volatile("s_waitcnt vmcnt(0)" ::: "memory");
    __syncthreads();

    const int G = blockIdx.x * 4 + w;
    const float* zr = Zl + w * 16 + lo;
    #pragma unroll
    for (int ks = 0; ks < 8; ks++) {
        union { short8 s; unsigned int d[4]; } u;
        #pragma unroll
        for (int j = 0; j < 4; j++) {
            int k = ks * 32 + hi * 8 + 2 * j;
            u.d[j] = bf2bits(__float22bfloat162_rn(
                make_float2(zr[k * 64], zr[(k + 1) * 64])));
        }
        *(short8*)((char*)Zbf + (size_t)(G * 8 + ks) * 1024 + l * 16) = u.s;
    }
}

// ---------------- kernel 2: bf16 MFMA GEMM + exact candidate argmin ----------------
// 1024 blocks (64 z-rows each), 256 threads = 4 waves, 16 rows/wave.
// ZERO LDS, zero barriers. A from Zbf (8 coalesced dwordx4); B dbl-buffered
// stream from L2-resident Ebf; eval np-exact from strided global Z (R8 path).
__global__ __launch_bounds__(256, 4) void gemm_argmin(const float* __restrict__ Z,
                                                      const unsigned short* __restrict__ Zbf,
                                                      const unsigned short* __restrict__ Ebf,
                                                      const float* __restrict__ E,
                                                      const float* __restrict__ Se,
                                                      int* __restrict__ idx_out,
                                                      int* __restrict__ full_list,
                                                      unsigned int* __restrict__ full_cnt) {
    const int t  = threadIdx.x;
    const int w  = t >> 6;
    const int l  = t & 63;
    const int lo = l & 15;
    const int hi = l >> 4;
    const int m0 = blockIdx.x * 64;
    const int b  = m0 >> 10;                    // 64 | 1024: never crosses b
    const int G  = blockIdx.x * 4 + w;

    // A-fragments: 8 coalesced 16B loads (bits identical to R10's af build)
    short8 af[8];
    #pragma unroll
    for (int ks = 0; ks < 8; ks++)
        af[ks] = *(const short8*)((const char*)Zbf + (size_t)(G * 8 + ks) * 1024 + l * 16);

    float v1[4], v2[4]; int i1[4];
    #pragma unroll
    for (int r = 0; r < 4; r++) { v1[r] = -1e30f; v2[r] = -1e30f; i1[r] = 0; }

    const unsigned short* ebl = Ebf + l * 8;

#define LOADB(buf, q_)                                                         \
    {                                                                          \
        const unsigned short* p_ = ebl + (size_t)(q_) * 4096;                  \
        _Pragma("unroll")                                                      \
        for (int ks = 0; ks < 8; ks++) buf[ks] = *(const short8*)(p_ + ks * 512); \
    }

#define COMPUTE(buf, q_)                                                       \
    {                                                                          \
        float hse = 0.5f * Se[(q_) * 16 + lo];                                 \
        floatx4 a0 = (floatx4){0.f, 0.f, 0.f, 0.f};                            \
        _Pragma("unroll")                                                      \
        for (int ks = 0; ks < 8; ks++)                                         \
            a0 = __builtin_amdgcn_mfma_f32_16x16x32_bf16(af[ks], buf[ks], a0, 0, 0, 0); \
        int n = (q_) * 16 + lo;                                                \
        _Pragma("unroll")                                                      \
        for (int r = 0; r < 4; r++) {                                          \
            float s0 = a0[r] - hse;                                            \
            if (s0 > v1[r])      { v2[r] = v1[r]; v1[r] = s0; i1[r] = n; }     \
            else if (s0 > v2[r]) { v2[r] = s0; }                               \
        }                                                                      \
    }

    short8 bA[8], bB[8];
    LOADB(bA, 0)
    #pragma unroll 1
    for (int q = 0; q < 64; q += 2) {
        LOADB(bB, q + 1)
        COMPUTE(bA, q)
        if (q < 62) LOADB(bA, q + 2)
        COMPUTE(bB, q + 1)
    }
#undef LOADB
#undef COMPUTE

    // per output row: merged top-1, ballots, candidate resolution (verbatim
    // R10 classification; eval = R8 np-exact order + R10 float4-er pipeline)
    #pragma unroll 1
    for (int r = 0; r < 4; r++) {
        float a1v = v1[r]; int ai = i1[r];
        #pragma unroll
        for (int mask = 1; mask < 16; mask <<= 1) {
            float o1 = __shfl_xor(a1v, mask);
            int   oi = __shfl_xor(ai, mask);
            if (o1 > a1v || (o1 == a1v && oi < ai)) { a1v = o1; ai = oi; }
        }
        float thresh = a1v - MARGIN;
        unsigned long long balF = __ballot(v2[r] >= thresh);
        unsigned long long balC = __ballot(v1[r] >= thresh);
        unsigned int fullq = (unsigned int)(balF >> (hi * 16)) & 0xFFFFu;
        unsigned int cm    = (unsigned int)(balC >> (hi * 16)) & 0xFFFFu;
        int m = __popc(cm);
        int rl  = w * 16 + hi * 4 + r;
        int row = m0 + rl;

        if (fullq) {
            // a lane may hide a 3rd+ candidate: full np-exact refine later
            if (lo == 0) {
                idx_out[row] = ai;  // placeholder, overwritten by refine_full
                unsigned int p = atomicAdd(full_cnt, 1u);
                if (p < FULL_CAP) full_list[p] = row;
            }
        } else if (m <= 1) {
            if (lo == 0) idx_out[row] = ai;
        } else {
            // candidate set == lane-top1s within margin (complete: any other k
            // would force its lane's top2 over thresh -> fullq). np-exact:
            // pairwise a8 sumsq + sequential-FMA dot, c ascending 0..255
            // (identical arithmetic/order to R8's validated inline eval).
            const int row_hw = (m0 & 1023) + rl;
            const float* zr = Z + (size_t)b * 262144 + row_hw;
            const float4* er4 = (const float4*)(E + (size_t)i1[r] * 256);
            float dot = 0.f;
            float a8[8];
            float blk0 = 0.f, blk1 = 0.f;
            float4 eA[8], eB[8];
#define EV(c_, ev_)                                                            \
    {                                                                          \
        float zv = zr[(c_) * 1024];                                           \
        if ((c_) % 128 < 8) a8[(c_) & 7] = __fmul_rn(zv, zv);                  \
        else a8[(c_) & 7] = __fadd_rn(a8[(c_) & 7], __fmul_rn(zv, zv));        \
        dot = __fmaf_rn(zv, (ev_), dot);                                       \
    }
#define A8TREE __fadd_rn(__fadd_rn(__fadd_rn(a8[0], a8[1]), __fadd_rn(a8[2], a8[3])), \
                         __fadd_rn(__fadd_rn(a8[4], a8[5]), __fadd_rn(a8[6], a8[7])))
            #pragma unroll
            for (int u = 0; u < 8; u++) eA[u] = er4[u];
            #pragma unroll
            for (int half = 0; half < 4; half++) {
                #pragma unroll
                for (int u = 0; u < 8; u++) eB[u] = er4[half * 16 + 8 + u];
                #pragma unroll
                for (int u = 0; u < 8; u++) {
                    int c = half * 64 + u * 4;
                    EV(c + 0, eA[u].x) EV(c + 1, eA[u].y)
                    EV(c + 2, eA[u].z) EV(c + 3, eA[u].w)
                }
                if (half < 3) {
                    #pragma unroll
                    for (int u = 0; u < 8; u++) eA[u] = er4[half * 16 + 16 + u];
                }
                #pragma unroll
                for (int u = 0; u < 8; u++) {
                    int c = half * 64 + 32 + u * 4;
                    EV(c + 0, eB[u].x) EV(c + 1, eB[u].y)
                    EV(c + 2, eB[u].z) EV(c + 3, eB[u].w)
                }
                if (half == 1) blk0 = A8TREE;
                if (half == 3) blk1 = A8TREE;
            }
#undef EV
#undef A8TREE
            float Sz = __fadd_rn(blk0, blk1);
            float dmy = 3.4e38f; int ky = 0x7fffffff;
            if ((cm >> lo) & 1u) {
                dmy = __fsub_rn(__fadd_rn(Sz, Se[i1[r]]), __fmul_rn(2.f, dot));
                ky = i1[r];
            }
            #pragma unroll
            for (int mask = 1; mask < 16; mask <<= 1) {
                float od = __shfl_xor(dmy, mask);
                int   ok = __shfl_xor(ky, mask);
                if (od < dmy || (od == dmy && ok < ky)) { dmy = od; ky = ok; }
            }
            if (lo == 0) idx_out[row] = ky;
        }
    }
}

// ---------------- kernel 3: LDS-staged full np-exact refine ----------------
// 16 rows per group; E staged in 32-row fp32 LDS tiles; stride 258 (2-way
// bank alias only). k ascending per thread, (d,k) lexicographic reduce ->
// np.argmin first-index semantics.
__global__ __launch_bounds__(256) void refine_full(const float* __restrict__ Z,
                                                   const float* __restrict__ E,
                                                   const float* __restrict__ Se,
                                                   const unsigned int* __restrict__ cnt,
                                                   const int* __restrict__ list,
                                                   int* __restrict__ idx_out) {
    __shared__ float zl[16 * 258];
    __shared__ float els[32 * 258];
    __shared__ float szs[16];
    __shared__ int rowid[16];
    unsigned int C = *cnt;
    if (C > FULL_CAP) C = FULL_CAP;
    const int t = threadIdx.x;
    const int kk = t & 31, rr = t >> 5;
    for (unsigned int base = blockIdx.x * 16; base < C; base += gridDim.x * 16) {
        int nrows = min(16, (int)(C - base));
        __syncthreads();
        if (t < 16) rowid[t] = list[base + (t < nrows ? t : 0)];
        __syncthreads();
        for (int i = 0; i < 16; i++) {
            int n = rowid[i];
            zl[i * 258 + t] = Z[(size_t)(n >> 10) * 262144 + t * 1024 + (n & 1023)];
        }
        __syncthreads();
        if (t < 16) szs[t] = np_pairwise_sumsq(&zl[t * 258]);

        float bd0 = 3.4e38f, bd1 = 3.4e38f; int bk0 = 0x7fffffff, bk1 = 0x7fffffff;
        for (int tile = 0; tile < 32; tile++) {
            __syncthreads();
            #pragma unroll
            for (int i = 0; i < 8; i++) {
                int chunk = i * 256 + t;
                int row = chunk >> 6, x = chunk & 63;
                float4 v = *(const float4*)(E + (tile * 32 + row) * 256 + x * 4);
                float* d = &els[row * 258 + x * 4];
                d[0] = v.x; d[1] = v.y; d[2] = v.z; d[3] = v.w;
            }
            __syncthreads();
            int k = tile * 32 + kk;
            const float* e  = &els[kk * 258];
            const float* za = &zl[rr * 258];
            const float* zb = &zl[(rr + 8) * 258];
            float a0 = 0.f, a1 = 0.f;
            for (int c = 0; c < 256; c += 2) {
                float2 e2 = *(const float2*)(e + c);
                float2 x2 = *(const float2*)(za + c);
                float2 y2 = *(const float2*)(zb + c);
                a0 = __fmaf_rn(x2.x, e2.x, a0); a0 = __fmaf_rn(x2.y, e2.y, a0);
                a1 = __fmaf_rn(y2.x, e2.x, a1); a1 = __fmaf_rn(y2.y, e2.y, a1);
            }
            float sek = Se[k];
            float d0 = __fsub_rn(__fadd_rn(szs[rr], sek),     __fmul_rn(2.f, a0));
            float d1 = __fsub_rn(__fadd_rn(szs[rr + 8], sek), __fmul_rn(2.f, a1));
            if (d0 < bd0) { bd0 = d0; bk0 = k; }
            if (d1 < bd1) { bd1 = d1; bk1 = k; }
        }
        #pragma unroll
        for (int mask = 1; mask < 32; mask <<= 1) {
            float od = __shfl_xor(bd0, mask); int ok = __shfl_xor(bk0, mask);
            if (od < bd0 || (od == bd0 && ok < bk0)) { bd0 = od; bk0 = ok; }
            od = __shfl_xor(bd1, mask); ok = __shfl_xor(bk1, mask);
            if (od < bd1 || (od == bd1 && ok < bk1)) { bd1 = od; bk1 = ok; }
        }
        if (kk == 0) {
            if (rr < nrows) idx_out[rowid[rr]] = bk0;
            if (rr + 8 < nrows) idx_out[rowid[rr + 8]] = bk1;
        }
    }
}

// ---------------- kernel 4: gather z_q (f32 out), fused loss ----------------
// E columns c0..c0+7 staged in LDS (pad *9) -> removes the 64-way L2
// row-gather per wave instruction. (R10-validated.)
__global__ __launch_bounds__(256) void gather_loss(const float* __restrict__ Z,
                                                   const float* __restrict__ E,
                                                   const int* __restrict__ idx,
                                                   float* __restrict__ out,
                                                   float* __restrict__ loss) {
    __shared__ int nl[1024];
    __shared__ float Ecol[1024 * 9];   // 36KB
    __shared__ float rs[256];
    const int t = threadIdx.x;
    const int blk = blockIdx.x;
    const int e0 = blk * 8192;
    const int b = blk >> 5;
    const int c0 = (blk & 31) * 8;     // (e0>>10)&255
    #pragma unroll
    for (int i = 0; i < 4; i++) nl[t + i * 256] = idx[b * 1024 + t + i * 256];
    #pragma unroll
    for (int i = 0; i < 4; i++) {
        int k = i * 256 + t;
        const float4* src = (const float4*)(E + k * 256 + c0);
        float4 v0 = src[0], v1 = src[1];
        float* d = &Ecol[k * 9];
        d[0] = v0.x; d[1] = v0.y; d[2] = v0.z; d[3] = v0.w;
        d[4] = v1.x; d[5] = v1.y; d[6] = v1.z; d[7] = v1.w;
    }
    __syncthreads();
    float ls = 0.f;
    #pragma unroll 4
    for (int i = 0; i < 32; i++) {
        int off = i * 256 + t;
        int hw = off & 1023;
        int coff = off >> 10;          // 0..7
        float q = Ecol[nl[hw] * 9 + coff];
        int e = e0 + off;
        out[e] = q;
        float d = q - Z[e];
        ls += d * d;
    }
    rs[t] = ls; __syncthreads();
    for (int s = 128; s > 0; s >>= 1) { if (t < s) rs[t] += rs[t + s]; __syncthreads(); }
    if (t == 0) atomicAdd(loss, rs[0]);
}

// ---------------- kernel 5: finalize loss + indices i32 -> float in place ----------------
__global__ __launch_bounds__(256) void finalize(const float* __restrict__ loss,
                                                float* __restrict__ out) {
    int g = blockIdx.x * 256 + threadIdx.x;
    if (g == 0) out[16777216] = 1.25f * (*loss) / 16777216.f;
    int raw = ((const int*)(out + IDX_OFF))[g];
    out[IDX_OFF + g] = b2f(f2b((float)raw));  // bf16 round-trip matches bf16-cast ref
}

extern "C" void kernel_launch(void* const* d_in, const int* in_sizes, int n_in,
                              void* d_out, int out_size, void* d_ws, size_t ws_size,
                              hipStream_t stream) {
    const float* Z = (const float*)d_in[0];
    const float* E = (const float*)d_in[1];
    float* out = (float*)d_out;
    char* ws = (char*)d_ws;
    float*        loss = (float*)ws;
    unsigned int* cnt  = (unsigned int*)(ws + 4);
    float*        Se   = (float*)(ws + 64);
    int*          list = (int*)(ws + 4352);
    int*          idx  = (int*)(out + IDX_OFF);
    // fragment-ordered bf16 operands live in the z_q output region (64MB),
    // consumed by gemm_argmin, overwritten afterwards by gather_loss:
    unsigned short* Zbf = (unsigned short*)out;                 // 32MB
    unsigned short* Ebf = (unsigned short*)(out + 8388608);     // 512KB at +32MB

    hipMemsetAsync(ws, 0, 8, stream);
    convert_e<<<128, 256, 0, stream>>>(E, Ebf, Se);
    convert_z<<<1024, 256, 0, stream>>>(Z, Zbf);
    gemm_argmin<<<1024, 256, 0, stream>>>(Z, Zbf, Ebf, E, Se, idx, list, cnt);
    refine_full<<<256, 256, 0, stream>>>(Z, E, Se, cnt, list, idx);
    gather_loss<<<2048, 256, 0, stream>>>(Z, E, idx, out, loss);
    finalize<<<256, 256, 0, stream>>>(loss, out);
}

// Round 6
// 570.993 us; speedup vs baseline: 2.6665x; 2.6665x over previous
//
#include <hip/hip_runtime.h>
#include <hip/hip_bf16.h>

// VectorQuantizer on MI355X (gfx950). Inputs fp32, output buffer fp32.
// z: [64,256,32,32] f32; E: [1024,256] f32.
// out (f32): z_q[16777216] | loss[1] | indices[65536] (float(idx), bf16-roundtrip)
//
// R12: zero-LDS gemm, pressure-bounded structurally (no launch_bounds arg2 --
// R11 showed (256,4) => VGPR cap 64 => 2.3GB spill traffic). Main-loop live
// set ~120 VGPR: af[8] (32) + dual-8 B buffers (64) + top2 state (12) + addr.
// A-fragments built in the prologue directly from strided global Z (R6's
// validated coalesced pattern) -- convert_z kernel dropped (saves 64MB
// round-trip + a launch). B = R8/R10-validated dbl-buffered L2 stream of
// fragment-ordered Ebf. Eval = R11's np-exact EV chain with 4+4 float4 er
// pipeline (32 VGPR, eval runs after B buffers die). All bit patterns match
// R6..R11 -> margin/ballot/refine machinery verbatim.
//
// out layout during pipeline: Ebf (frag-ordered bf16 E, 512KB) at out[0],
// consumed by gemm_argmin, overwritten afterwards by gather_loss.
// ws: [0,4) loss f32 | [4,8) full cnt | [64,4160) Se[1024] | [4352,+32K) full list

typedef __attribute__((ext_vector_type(8))) short short8;
typedef __attribute__((ext_vector_type(4))) float floatx4;

#define MARGIN 2.5e-4f
#define FULL_CAP 8192u
#define IDX_OFF 16777217

__device__ __forceinline__ unsigned short f2b(float f) {
    union { float f; unsigned int i; } x; x.f = f;
    unsigned int i = x.i;
    unsigned int r = (i + 0x7fffu + ((i >> 16) & 1u)) >> 16;  // RN-even
    return (unsigned short)r;
}
__device__ __forceinline__ float b2f(unsigned short u) {
    union { unsigned int i; float f; } x; x.i = ((unsigned int)u) << 16; return x.f;
}
__device__ __forceinline__ unsigned int bf2bits(__hip_bfloat162 h) {
    union { __hip_bfloat162 h; unsigned int u; } x; x.h = h; return x.u;
}

// numpy pairwise sum of squares, n=256 contiguous: 128+128, each with 8
// stride-8 accumulators, combine ((r0+r1)+(r2+r3))+((r4+r5)+(r6+r7)).
__device__ __forceinline__ float np_pairwise_sumsq(const float* __restrict__ a) {
    float blk[2];
    #pragma unroll
    for (int h = 0; h < 2; h++) {
        const float* p = a + h * 128;
        float r0 = __fmul_rn(p[0], p[0]), r1 = __fmul_rn(p[1], p[1]);
        float r2 = __fmul_rn(p[2], p[2]), r3 = __fmul_rn(p[3], p[3]);
        float r4 = __fmul_rn(p[4], p[4]), r5 = __fmul_rn(p[5], p[5]);
        float r6 = __fmul_rn(p[6], p[6]), r7 = __fmul_rn(p[7], p[7]);
        for (int i = 8; i < 128; i += 8) {
            r0 = __fadd_rn(r0, __fmul_rn(p[i + 0], p[i + 0]));
            r1 = __fadd_rn(r1, __fmul_rn(p[i + 1], p[i + 1]));
            r2 = __fadd_rn(r2, __fmul_rn(p[i + 2], p[i + 2]));
            r3 = __fadd_rn(r3, __fmul_rn(p[i + 3], p[i + 3]));
            r4 = __fadd_rn(r4, __fmul_rn(p[i + 4], p[i + 4]));
            r5 = __fadd_rn(r5, __fmul_rn(p[i + 5], p[i + 5]));
            r6 = __fadd_rn(r6, __fmul_rn(p[i + 6], p[i + 6]));
            r7 = __fadd_rn(r7, __fmul_rn(p[i + 7], p[i + 7]));
        }
        blk[h] = __fadd_rn(__fadd_rn(__fadd_rn(r0, r1), __fadd_rn(r2, r3)),
                           __fadd_rn(__fadd_rn(r4, r5), __fadd_rn(r6, r7)));
    }
    return __fadd_rn(blk[0], blk[1]);
}

// ---------------- kernel 1: E f32 -> bf16 fragment order, + Se ----------------
// Element (n,k) -> group g = ((nt*4+nf)*8+ks)*4+hi, slot lo*8+j (validated
// R7..R11). Blocks 0-3 additionally compute Se[k] np-exact.
__global__ __launch_bounds__(256) void convert_e(const float* __restrict__ E,
                                                 unsigned short* __restrict__ Ebf,
                                                 float* __restrict__ Se) {
    int t = blockIdx.x * 256 + threadIdx.x;
    int n = t >> 5;
    int oct = t & 31;                 // k-octet: k = oct*8 + j ; ks=oct>>2, hi=oct&3
    int nt = n >> 6, nf = (n >> 4) & 3, lo = n & 15;
    int g = ((nt * 4 + nf) * 8 + (oct >> 2)) * 4 + (oct & 3);
    const float* src = E + n * 256 + oct * 8;
    union { short8 s; unsigned int d[4]; } u;
    #pragma unroll
    for (int j = 0; j < 4; j++)
        u.d[j] = bf2bits(__float22bfloat162_rn(make_float2(src[2 * j], src[2 * j + 1])));
    *(short8*)(Ebf + g * 128 + lo * 8) = u.s;
    if (blockIdx.x < 4) {
        int k = blockIdx.x * 256 + threadIdx.x;
        Se[k] = np_pairwise_sumsq(E + k * 256);
    }
}

// ---------------- kernel 2: bf16 MFMA GEMM + exact candidate argmin ----------------
// 1024 blocks (64 z-rows each), 256 threads = 4 waves, 16 rows/wave.
// ZERO LDS, zero barriers. A packed in prologue from strided global Z (R6
// pattern, 16-lane-coalesced 64B segments); B dbl-buffered L2 stream; eval
// np-exact from strided global Z (R8/R11 path, 4+4 float4 er pipeline).
__global__ __launch_bounds__(256) void gemm_argmin(const float* __restrict__ Z,
                                                   const unsigned short* __restrict__ Ebf,
                                                   const float* __restrict__ E,
                                                   const float* __restrict__ Se,
                                                   int* __restrict__ idx_out,
                                                   int* __restrict__ full_list,
                                                   unsigned int* __restrict__ full_cnt) {
    const int t  = threadIdx.x;
    const int w  = t >> 6;
    const int l  = t & 63;
    const int lo = l & 15;
    const int hi = l >> 4;
    const int m0 = blockIdx.x * 64;
    const int b  = m0 >> 10;                    // 64 | 1024: never crosses b
    const int hw = (m0 & 1023) + w * 16 + lo;
    const float* zs = Z + (size_t)b * 262144 + hw;

    // A-fragments: A[m=lo][k=hi*8+j], packed fp32->bf16 (R6-validated build)
    short8 af[8];
    #pragma unroll
    for (int ks = 0; ks < 8; ks++) {
        union { short8 s; unsigned int d[4]; } u;
        #pragma unroll
        for (int j = 0; j < 4; j++) {
            float a0 = zs[(ks * 32 + hi * 8 + 2 * j) * 1024];
            float a1 = zs[(ks * 32 + hi * 8 + 2 * j + 1) * 1024];
            u.d[j] = bf2bits(__float22bfloat162_rn(make_float2(a0, a1)));
        }
        af[ks] = u.s;
    }

    float v1[4], v2[4]; int i1[4];
    #pragma unroll
    for (int r = 0; r < 4; r++) { v1[r] = -1e30f; v2[r] = -1e30f; i1[r] = 0; }

    // B-fragment stream from L2-resident Ebf (validated layout): fragment
    // (q,ks) = 1KB at (q*8+ks)*1024 bytes, lane slice +l*16.
    const unsigned short* ebl = Ebf + l * 8;

#define LOADB(buf, q_)                                                         \
    {                                                                          \
        const unsigned short* p_ = ebl + (size_t)(q_) * 4096;                  \
        _Pragma("unroll")                                                      \
        for (int ks = 0; ks < 8; ks++) buf[ks] = *(const short8*)(p_ + ks * 512); \
    }

#define COMPUTE(buf, q_)                                                       \
    {                                                                          \
        float hse = 0.5f * Se[(q_) * 16 + lo];                                 \
        floatx4 a0 = (floatx4){0.f, 0.f, 0.f, 0.f};                            \
        _Pragma("unroll")                                                      \
        for (int ks = 0; ks < 8; ks++)                                         \
            a0 = __builtin_amdgcn_mfma_f32_16x16x32_bf16(af[ks], buf[ks], a0, 0, 0, 0); \
        int n = (q_) * 16 + lo;                                                \
        _Pragma("unroll")                                                      \
        for (int r = 0; r < 4; r++) {                                          \
            float s0 = a0[r] - hse;                                            \
            if (s0 > v1[r])      { v2[r] = v1[r]; v1[r] = s0; i1[r] = n; }     \
            else if (s0 > v2[r]) { v2[r] = s0; }                               \
        }                                                                      \
    }

    short8 bA[8], bB[8];
    LOADB(bA, 0)
    #pragma unroll 1
    for (int q = 0; q < 64; q += 2) {
        LOADB(bB, q + 1)
        COMPUTE(bA, q)
        if (q < 62) LOADB(bA, q + 2)
        COMPUTE(bB, q + 1)
    }
#undef LOADB
#undef COMPUTE

    // per output row: merged top-1, ballots, candidate resolution (verbatim
    // R10/R11 classification; eval = R8/R11 np-exact order, 4+4 er pipeline)
    #pragma unroll 1
    for (int r = 0; r < 4; r++) {
        float a1v = v1[r]; int ai = i1[r];
        #pragma unroll
        for (int mask = 1; mask < 16; mask <<= 1) {
            float o1 = __shfl_xor(a1v, mask);
            int   oi = __shfl_xor(ai, mask);
            if (o1 > a1v || (o1 == a1v && oi < ai)) { a1v = o1; ai = oi; }
        }
        float thresh = a1v - MARGIN;
        unsigned long long balF = __ballot(v2[r] >= thresh);
        unsigned long long balC = __ballot(v1[r] >= thresh);
        unsigned int fullq = (unsigned int)(balF >> (hi * 16)) & 0xFFFFu;
        unsigned int cm    = (unsigned int)(balC >> (hi * 16)) & 0xFFFFu;
        int m = __popc(cm);
        int rl  = w * 16 + hi * 4 + r;
        int row = m0 + rl;

        if (fullq) {
            // a lane may hide a 3rd+ candidate: full np-exact refine later
            if (lo == 0) {
                idx_out[row] = ai;  // placeholder, overwritten by refine_full
                unsigned int p = atomicAdd(full_cnt, 1u);
                if (p < FULL_CAP) full_list[p] = row;
            }
        } else if (m <= 1) {
            if (lo == 0) idx_out[row] = ai;
        } else {
            // candidate set == lane-top1s within margin (complete: any other k
            // would force its lane's top2 over thresh -> fullq). np-exact:
            // pairwise a8 sumsq + sequential-FMA dot, c ascending 0..255
            // (identical arithmetic/order to R8/R11's validated inline eval).
            const int row_hw = (m0 & 1023) + rl;
            const float* zr = Z + (size_t)b * 262144 + row_hw;
            const float4* er4 = (const float4*)(E + (size_t)i1[r] * 256);
            float dot = 0.f;
            float a8[8];
            float blk0 = 0.f, blk1 = 0.f;
            float4 eA[4], eB[4];
#define EV(c_, ev_)                                                            \
    {                                                                          \
        float zv = zr[(c_) * 1024];                                           \
        if ((c_) % 128 < 8) a8[(c_) & 7] = __fmul_rn(zv, zv);                  \
        else a8[(c_) & 7] = __fadd_rn(a8[(c_) & 7], __fmul_rn(zv, zv));        \
        dot = __fmaf_rn(zv, (ev_), dot);                                       \
    }
#define A8TREE __fadd_rn(__fadd_rn(__fadd_rn(a8[0], a8[1]), __fadd_rn(a8[2], a8[3])), \
                         __fadd_rn(__fadd_rn(a8[4], a8[5]), __fadd_rn(a8[6], a8[7])))
#define LOADG(buf, g_)                                                         \
    { _Pragma("unroll") for (int u = 0; u < 4; u++) buf[u] = er4[(g_) * 4 + u]; }
#define EVG(buf, g_)                                                           \
    {                                                                          \
        _Pragma("unroll")                                                      \
        for (int u = 0; u < 4; u++) {                                          \
            int c = (g_) * 16 + u * 4;                                         \
            EV(c + 0, buf[u].x) EV(c + 1, buf[u].y)                            \
            EV(c + 2, buf[u].z) EV(c + 3, buf[u].w)                            \
        }                                                                      \
    }
            LOADG(eA, 0)
            LOADG(eB, 1) EVG(eA, 0)
            LOADG(eA, 2) EVG(eB, 1)
            LOADG(eB, 3) EVG(eA, 2)
            LOADG(eA, 4) EVG(eB, 3)
            LOADG(eB, 5) EVG(eA, 4)
            LOADG(eA, 6) EVG(eB, 5)
            LOADG(eB, 7) EVG(eA, 6)
            LOADG(eA, 8) EVG(eB, 7)
            blk0 = A8TREE;
            LOADG(eB, 9)  EVG(eA, 8)
            LOADG(eA, 10) EVG(eB, 9)
            LOADG(eB, 11) EVG(eA, 10)
            LOADG(eA, 12) EVG(eB, 11)
            LOADG(eB, 13) EVG(eA, 12)
            LOADG(eA, 14) EVG(eB, 13)
            LOADG(eB, 15) EVG(eA, 14)
            EVG(eB, 15)
            blk1 = A8TREE;
#undef EV
#undef A8TREE
#undef LOADG
#undef EVG
            float Sz = __fadd_rn(blk0, blk1);
            float dmy = 3.4e38f; int ky = 0x7fffffff;
            if ((cm >> lo) & 1u) {
                dmy = __fsub_rn(__fadd_rn(Sz, Se[i1[r]]), __fmul_rn(2.f, dot));
                ky = i1[r];
            }
            #pragma unroll
            for (int mask = 1; mask < 16; mask <<= 1) {
                float od = __shfl_xor(dmy, mask);
                int   ok = __shfl_xor(ky, mask);
                if (od < dmy || (od == dmy && ok < ky)) { dmy = od; ky = ok; }
            }
            if (lo == 0) idx_out[row] = ky;
        }
    }
}

// ---------------- kernel 3: LDS-staged full np-exact refine ----------------
// 16 rows per group; E staged in 32-row fp32 LDS tiles; stride 258 (2-way
// bank alias only). k ascending per thread, (d,k) lexicographic reduce ->
// np.argmin first-index semantics.
__global__ __launch_bounds__(256) void refine_full(const float* __restrict__ Z,
                                                   const float* __restrict__ E,
                                                   const float* __restrict__ Se,
                                                   const unsigned int* __restrict__ cnt,
                                                   const int* __restrict__ list,
                                                   int* __restrict__ idx_out) {
    __shared__ float zl[16 * 258];
    __shared__ float els[32 * 258];
    __shared__ float szs[16];
    __shared__ int rowid[16];
    unsigned int C = *cnt;
    if (C > FULL_CAP) C = FULL_CAP;
    const int t = threadIdx.x;
    const int kk = t & 31, rr = t >> 5;
    for (unsigned int base = blockIdx.x * 16; base < C; base += gridDim.x * 16) {
        int nrows = min(16, (int)(C - base));
        __syncthreads();
        if (t < 16) rowid[t] = list[base + (t < nrows ? t : 0)];
        __syncthreads();
        for (int i = 0; i < 16; i++) {
            int n = rowid[i];
            zl[i * 258 + t] = Z[(size_t)(n >> 10) * 262144 + t * 1024 + (n & 1023)];
        }
        __syncthreads();
        if (t < 16) szs[t] = np_pairwise_sumsq(&zl[t * 258]);

        float bd0 = 3.4e38f, bd1 = 3.4e38f; int bk0 = 0x7fffffff, bk1 = 0x7fffffff;
        for (int tile = 0; tile < 32; tile++) {
            __syncthreads();
            #pragma unroll
            for (int i = 0; i < 8; i++) {
                int chunk = i * 256 + t;
                int row = chunk >> 6, x = chunk & 63;
                float4 v = *(const float4*)(E + (tile * 32 + row) * 256 + x * 4);
                float* d = &els[row * 258 + x * 4];
                d[0] = v.x; d[1] = v.y; d[2] = v.z; d[3] = v.w;
            }
            __syncthreads();
            int k = tile * 32 + kk;
            const float* e  = &els[kk * 258];
            const float* za = &zl[rr * 258];
            const float* zb = &zl[(rr + 8) * 258];
            float a0 = 0.f, a1 = 0.f;
            for (int c = 0; c < 256; c += 2) {
                float2 e2 = *(const float2*)(e + c);
                float2 x2 = *(const float2*)(za + c);
                float2 y2 = *(const float2*)(zb + c);
                a0 = __fmaf_rn(x2.x, e2.x, a0); a0 = __fmaf_rn(x2.y, e2.y, a0);
                a1 = __fmaf_rn(y2.x, e2.x, a1); a1 = __fmaf_rn(y2.y, e2.y, a1);
            }
            float sek = Se[k];
            float d0 = __fsub_rn(__fadd_rn(szs[rr], sek),     __fmul_rn(2.f, a0));
            float d1 = __fsub_rn(__fadd_rn(szs[rr + 8], sek), __fmul_rn(2.f, a1));
            if (d0 < bd0) { bd0 = d0; bk0 = k; }
            if (d1 < bd1) { bd1 = d1; bk1 = k; }
        }
        #pragma unroll
        for (int mask = 1; mask < 32; mask <<= 1) {
            float od = __shfl_xor(bd0, mask); int ok = __shfl_xor(bk0, mask);
            if (od < bd0 || (od == bd0 && ok < bk0)) { bd0 = od; bk0 = ok; }
            od = __shfl_xor(bd1, mask); ok = __shfl_xor(bk1, mask);
            if (od < bd1 || (od == bd1 && ok < bk1)) { bd1 = od; bk1 = ok; }
        }
        if (kk == 0) {
            if (rr < nrows) idx_out[rowid[rr]] = bk0;
            if (rr + 8 < nrows) idx_out[rowid[rr + 8]] = bk1;
        }
    }
}

// ---------------- kernel 4: gather z_q (f32 out), fused loss ----------------
// E columns c0..c0+7 staged in LDS (pad *9) -> removes the 64-way L2
// row-gather per wave instruction. (R10-validated.)
__global__ __launch_bounds__(256) void gather_loss(const float* __restrict__ Z,
                                                   const float* __restrict__ E,
                                                   const int* __restrict__ idx,
                                                   float* __restrict__ out,
                                                   float* __restrict__ loss) {
    __shared__ int nl[1024];
    __shared__ float Ecol[1024 * 9];   // 36KB
    __shared__ float rs[256];
    const int t = threadIdx.x;
    const int blk = blockIdx.x;
    const int e0 = blk * 8192;
    const int b = blk >> 5;
    const int c0 = (blk & 31) * 8;     // (e0>>10)&255
    #pragma unroll
    for (int i = 0; i < 4; i++) nl[t + i * 256] = idx[b * 1024 + t + i * 256];
    #pragma unroll
    for (int i = 0; i < 4; i++) {
        int k = i * 256 + t;
        const float4* src = (const float4*)(E + k * 256 + c0);
        float4 v0 = src[0], v1 = src[1];
        float* d = &Ecol[k * 9];
        d[0] = v0.x; d[1] = v0.y; d[2] = v0.z; d[3] = v0.w;
        d[4] = v1.x; d[5] = v1.y; d[6] = v1.z; d[7] = v1.w;
    }
    __syncthreads();
    float ls = 0.f;
    #pragma unroll 4
    for (int i = 0; i < 32; i++) {
        int off = i * 256 + t;
        int hw = off & 1023;
        int coff = off >> 10;          // 0..7
        float q = Ecol[nl[hw] * 9 + coff];
        int e = e0 + off;
        out[e] = q;
        float d = q - Z[e];
        ls += d * d;
    }
    rs[t] = ls; __syncthreads();
    for (int s = 128; s > 0; s >>= 1) { if (t < s) rs[t] += rs[t + s]; __syncthreads(); }
    if (t == 0) atomicAdd(loss, rs[0]);
}

// ---------------- kernel 5: finalize loss + indices i32 -> float in place ----------------
__global__ __launch_bounds__(256) void finalize(const float* __restrict__ loss,
                                                float* __restrict__ out) {
    int g = blockIdx.x * 256 + threadIdx.x;
    if (g == 0) out[16777216] = 1.25f * (*loss) / 16777216.f;
    int raw = ((const int*)(out + IDX_OFF))[g];
    out[IDX_OFF + g] = b2f(f2b((float)raw));  // bf16 round-trip matches bf16-cast ref
}

extern "C" void kernel_launch(void* const* d_in, const int* in_sizes, int n_in,
                              void* d_out, int out_size, void* d_ws, size_t ws_size,
                              hipStream_t stream) {
    const float* Z = (const float*)d_in[0];
    const float* E = (const float*)d_in[1];
    float* out = (float*)d_out;
    char* ws = (char*)d_ws;
    float*        loss = (float*)ws;
    unsigned int* cnt  = (unsigned int*)(ws + 4);
    float*        Se   = (float*)(ws + 64);
    int*          list = (int*)(ws + 4352);
    int*          idx  = (int*)(out + IDX_OFF);
    // bf16 fragment-ordered E lives in the z_q output region (512 KiB),
    // consumed by gemm_argmin, overwritten afterwards by gather_loss.
    unsigned short* Ebf = (unsigned short*)out;

    hipMemsetAsync(ws, 0, 8, stream);
    convert_e<<<128, 256, 0, stream>>>(E, Ebf, Se);
    gemm_argmin<<<1024, 256, 0, stream>>>(Z, Ebf, E, Se, idx, list, cnt);
    refine_full<<<256, 256, 0, stream>>>(Z, E, Se, cnt, list, idx);
    gather_loss<<<2048, 256, 0, stream>>>(Z, E, idx, out, loss);
    finalize<<<256, 256, 0, stream>>>(loss, out);
}

// Round 7
// 474.434 us; speedup vs baseline: 3.2092x; 1.2035x over previous
//
#include <hip/hip_runtime.h>
#include <hip/hip_bf16.h>

// VectorQuantizer on MI355X (gfx950). Inputs fp32, output buffer fp32.
// z: [64,256,32,32] f32; E: [1024,256] f32.
// out (f32): z_q[16777216] | loss[1] | indices[65536] (float(idx), bf16-roundtrip)
//
// R13: zero-LDS gemm + exported ambiguity resolution.
//  - gemm: R11's validated loop (A from fragment-ordered Zbf, dbl-buffered B
//    stream from L2-resident Ebf), NO launch_bounds arg2 (R11 lesson), NO LDS,
//    NO barriers, and NO inline eval: m>=2 rows export {row, 16 candidates}.
//    Live set ~125 VGPR -> 3-4 waves/SIMD (vs R10's 2).
//  - eval_ambig: resolves exported rows with refine_full's validated staging
//    (Z is L3-resident), Sz via refine-validated contiguous pairwise tree,
//    dot = R10's validated ascending-c float4-er pipeline. Bit-identical
//    decisions; serial FMA chains now hidden by high occupancy.
//  - convert_z (R11-validated bits) supplies Zbf.
// All score/eval bit patterns match R6..R12 -> margin/ballot/refine verbatim.
//
// out region map during pipeline (all dead before gather_loss writes):
//   Ebf   [0, 512KB)        frag-ordered bf16 E
//   rowid [1MB, 1.25MB)     eval row list (<=65536)
//   cands [1.25MB, 5.25MB)  16 int candidates per eval row
//   Zbf   [8MB, 40MB)       frag-ordered bf16 Z
// ws: [0,4) loss | [4,8) full cnt | [8,12) eval cnt | [64,4160) Se | [4352,+32K) full list

typedef __attribute__((ext_vector_type(8))) short short8;
typedef __attribute__((ext_vector_type(4))) float floatx4;

#define MARGIN 2.5e-4f
#define FULL_CAP 8192u
#define IDX_OFF 16777217

__device__ __forceinline__ unsigned short f2b(float f) {
    union { float f; unsigned int i; } x; x.f = f;
    unsigned int i = x.i;
    unsigned int r = (i + 0x7fffu + ((i >> 16) & 1u)) >> 16;  // RN-even
    return (unsigned short)r;
}
__device__ __forceinline__ float b2f(unsigned short u) {
    union { unsigned int i; float f; } x; x.i = ((unsigned int)u) << 16; return x.f;
}
__device__ __forceinline__ unsigned int bf2bits(__hip_bfloat162 h) {
    union { __hip_bfloat162 h; unsigned int u; } x; x.h = h; return x.u;
}

// numpy pairwise sum of squares, n=256 contiguous: 128+128, each with 8
// stride-8 accumulators, combine ((r0+r1)+(r2+r3))+((r4+r5)+(r6+r7)).
__device__ __forceinline__ float np_pairwise_sumsq(const float* __restrict__ a) {
    float blk[2];
    #pragma unroll
    for (int h = 0; h < 2; h++) {
        const float* p = a + h * 128;
        float r0 = __fmul_rn(p[0], p[0]), r1 = __fmul_rn(p[1], p[1]);
        float r2 = __fmul_rn(p[2], p[2]), r3 = __fmul_rn(p[3], p[3]);
        float r4 = __fmul_rn(p[4], p[4]), r5 = __fmul_rn(p[5], p[5]);
        float r6 = __fmul_rn(p[6], p[6]), r7 = __fmul_rn(p[7], p[7]);
        for (int i = 8; i < 128; i += 8) {
            r0 = __fadd_rn(r0, __fmul_rn(p[i + 0], p[i + 0]));
            r1 = __fadd_rn(r1, __fmul_rn(p[i + 1], p[i + 1]));
            r2 = __fadd_rn(r2, __fmul_rn(p[i + 2], p[i + 2]));
            r3 = __fadd_rn(r3, __fmul_rn(p[i + 3], p[i + 3]));
            r4 = __fadd_rn(r4, __fmul_rn(p[i + 4], p[i + 4]));
            r5 = __fadd_rn(r5, __fmul_rn(p[i + 5], p[i + 5]));
            r6 = __fadd_rn(r6, __fmul_rn(p[i + 6], p[i + 6]));
            r7 = __fadd_rn(r7, __fmul_rn(p[i + 7], p[i + 7]));
        }
        blk[h] = __fadd_rn(__fadd_rn(__fadd_rn(r0, r1), __fadd_rn(r2, r3)),
                           __fadd_rn(__fadd_rn(r4, r5), __fadd_rn(r6, r7)));
    }
    return __fadd_rn(blk[0], blk[1]);
}

// ---------------- kernel 1a: E f32 -> bf16 fragment order, + Se ----------------
__global__ __launch_bounds__(256) void convert_e(const float* __restrict__ E,
                                                 unsigned short* __restrict__ Ebf,
                                                 float* __restrict__ Se) {
    int t = blockIdx.x * 256 + threadIdx.x;
    int n = t >> 5;
    int oct = t & 31;                 // k-octet: k = oct*8 + j ; ks=oct>>2, hi=oct&3
    int nt = n >> 6, nf = (n >> 4) & 3, lo = n & 15;
    int g = ((nt * 4 + nf) * 8 + (oct >> 2)) * 4 + (oct & 3);
    const float* src = E + n * 256 + oct * 8;
    union { short8 s; unsigned int d[4]; } u;
    #pragma unroll
    for (int j = 0; j < 4; j++)
        u.d[j] = bf2bits(__float22bfloat162_rn(make_float2(src[2 * j], src[2 * j + 1])));
    *(short8*)(Ebf + g * 128 + lo * 8) = u.s;
    if (blockIdx.x < 4) {
        int k = blockIdx.x * 256 + threadIdx.x;
        Se[k] = np_pairwise_sumsq(E + k * 256);
    }
}

// ---------------- kernel 1b: Z f32 -> bf16 A-fragment order (R11-validated) ----------------
__global__ __launch_bounds__(256) void convert_z(const float* __restrict__ Z,
                                                 unsigned short* __restrict__ Zbf) {
    __shared__ __align__(16) float Zl[16384];   // [c][x]: c*64 + x
    const int t  = threadIdx.x;
    const int w  = t >> 6;
    const int l  = t & 63;
    const int lo = l & 15;
    const int hi = l >> 4;
    const int m0 = blockIdx.x * 64;
    const int b  = m0 >> 10;
    const int hwb = m0 & 1023;
    const float* Zb = Z + (size_t)b * 262144;

    #pragma unroll
    for (int j = 0; j < 16; j++) {
        int iw = w + j * 4;
        __builtin_amdgcn_global_load_lds(
            (const __attribute__((address_space(1))) unsigned int*)
                (Zb + (iw * 4 + hi) * 1024 + hwb + lo * 4),
            (__attribute__((address_space(3))) unsigned int*)((char*)Zl + iw * 1024),
            16, 0, 0);
    }
    asm volatile("s_waitcnt vmcnt(0)" ::: "memory");
    __syncthreads();

    const int G = blockIdx.x * 4 + w;
    const float* zr = Zl + w * 16 + lo;
    #pragma unroll
    for (int ks = 0; ks < 8; ks++) {
        union { short8 s; unsigned int d[4]; } u;
        #pragma unroll
        for (int j = 0; j < 4; j++) {
            int k = ks * 32 + hi * 8 + 2 * j;
            u.d[j] = bf2bits(__float22bfloat162_rn(
                make_float2(zr[k * 64], zr[(k + 1) * 64])));
        }
        *(short8*)((char*)Zbf + (size_t)(G * 8 + ks) * 1024 + l * 16) = u.s;
    }
}

// ---------------- kernel 2: bf16 MFMA GEMM + candidate classification ----------------
// 1024 blocks (64 z-rows each), 256 threads = 4 waves, 16 rows/wave.
// ZERO LDS, zero barriers, no inline eval. m>=2 rows exported to eval_ambig.
__global__ __launch_bounds__(256) void gemm_argmin(const unsigned short* __restrict__ Zbf,
                                                   const unsigned short* __restrict__ Ebf,
                                                   const float* __restrict__ Se,
                                                   int* __restrict__ idx_out,
                                                   int* __restrict__ full_list,
                                                   unsigned int* __restrict__ full_cnt,
                                                   int* __restrict__ ev_rowid,
                                                   int* __restrict__ ev_cands,
                                                   unsigned int* __restrict__ ev_cnt) {
    const int t  = threadIdx.x;
    const int w  = t >> 6;
    const int l  = t & 63;
    const int lo = l & 15;
    const int hi = l >> 4;
    const int m0 = blockIdx.x * 64;
    const int G  = blockIdx.x * 4 + w;

    // A-fragments: 8 coalesced 16B loads (bits identical to R10/R11 af build)
    short8 af[8];
    #pragma unroll
    for (int ks = 0; ks < 8; ks++)
        af[ks] = *(const short8*)((const char*)Zbf + (size_t)(G * 8 + ks) * 1024 + l * 16);

    float v1[4], v2[4]; int i1[4];
    #pragma unroll
    for (int r = 0; r < 4; r++) { v1[r] = -1e30f; v2[r] = -1e30f; i1[r] = 0; }

    const unsigned short* ebl = Ebf + l * 8;

#define LOADB(buf, q_)                                                         \
    {                                                                          \
        const unsigned short* p_ = ebl + (size_t)(q_) * 4096;                  \
        _Pragma("unroll")                                                      \
        for (int ks = 0; ks < 8; ks++) buf[ks] = *(const short8*)(p_ + ks * 512); \
    }

#define COMPUTE(buf, q_)                                                       \
    {                                                                          \
        float hse = 0.5f * Se[(q_) * 16 + lo];                                 \
        floatx4 a0 = (floatx4){0.f, 0.f, 0.f, 0.f};                            \
        _Pragma("unroll")                                                      \
        for (int ks = 0; ks < 8; ks++)                                         \
            a0 = __builtin_amdgcn_mfma_f32_16x16x32_bf16(af[ks], buf[ks], a0, 0, 0, 0); \
        int n = (q_) * 16 + lo;                                                \
        _Pragma("unroll")                                                      \
        for (int r = 0; r < 4; r++) {                                          \
            float s0 = a0[r] - hse;                                            \
            if (s0 > v1[r])      { v2[r] = v1[r]; v1[r] = s0; i1[r] = n; }     \
            else if (s0 > v2[r]) { v2[r] = s0; }                               \
        }                                                                      \
    }

    short8 bA[8], bB[8];
    LOADB(bA, 0)
    #pragma unroll 1
    for (int q = 0; q < 64; q += 2) {
        LOADB(bB, q + 1)
        COMPUTE(bA, q)
        if (q < 62) LOADB(bA, q + 2)
        COMPUTE(bB, q + 1)
    }
#undef LOADB
#undef COMPUTE

    // per output row: merged top-1, ballots, classification (verbatim R10);
    // m>=2 -> export candidate set for eval_ambig
    #pragma unroll 1
    for (int r = 0; r < 4; r++) {
        float a1v = v1[r]; int ai = i1[r];
        #pragma unroll
        for (int mask = 1; mask < 16; mask <<= 1) {
            float o1 = __shfl_xor(a1v, mask);
            int   oi = __shfl_xor(ai, mask);
            if (o1 > a1v || (o1 == a1v && oi < ai)) { a1v = o1; ai = oi; }
        }
        float thresh = a1v - MARGIN;
        unsigned long long balF = __ballot(v2[r] >= thresh);
        unsigned long long balC = __ballot(v1[r] >= thresh);
        unsigned int fullq = (unsigned int)(balF >> (hi * 16)) & 0xFFFFu;
        unsigned int cm    = (unsigned int)(balC >> (hi * 16)) & 0xFFFFu;
        int m = __popc(cm);
        int rl  = w * 16 + hi * 4 + r;
        int row = m0 + rl;

        if (fullq) {
            // a lane may hide a 3rd+ candidate: full np-exact refine later
            if (lo == 0) {
                idx_out[row] = ai;  // placeholder, overwritten by refine_full
                unsigned int p = atomicAdd(full_cnt, 1u);
                if (p < FULL_CAP) full_list[p] = row;
            }
        } else if (m <= 1) {
            if (lo == 0) idx_out[row] = ai;
        } else {
            // candidate set == lane-top1s within margin (complete: any other k
            // would force its lane's top2 over thresh -> fullq). Export for
            // np-exact resolution in eval_ambig (capacity 65536 >= all rows).
            int p = 0;
            if (lo == 0) {
                idx_out[row] = ai;  // placeholder, overwritten by eval_ambig
                p = (int)atomicAdd(ev_cnt, 1u);
                ev_rowid[p] = row;
            }
            p = __shfl(p, hi * 16);
            ev_cands[p * 16 + lo] = ((cm >> lo) & 1u) ? i1[r] : -1;
        }
    }
}

// ---------------- kernel 2b: np-exact resolution of exported candidate sets ----------------
// 16 rows per block-iter; z staged refine-style (L3-resident), Sz via the
// refine-validated contiguous pairwise tree; dot = R10's validated ascending-c
// float4-er pipeline; same sentinel/shfl reduce -> bit-identical decisions.
__global__ __launch_bounds__(256) void eval_ambig(const float* __restrict__ Z,
                                                  const float* __restrict__ E,
                                                  const float* __restrict__ Se,
                                                  const unsigned int* __restrict__ cnt,
                                                  const int* __restrict__ rowid,
                                                  const int* __restrict__ cands,
                                                  int* __restrict__ idx_out) {
    __shared__ float zl[16 * 258];
    __shared__ float szs[16];
    __shared__ int rid[16];
    unsigned int C = *cnt;
    const int t = threadIdx.x;
    const int g = t >> 4, j = t & 15;
    for (unsigned int base = blockIdx.x * 16; base < C; base += gridDim.x * 16) {
        __syncthreads();
        if (t < 16) {
            unsigned int s = base + t;
            rid[t] = rowid[s < C ? s : C - 1];
        }
        __syncthreads();
        for (int i = 0; i < 16; i++) {
            int n = rid[i];
            zl[i * 258 + t] = Z[(size_t)(n >> 10) * 262144 + t * 1024 + (n & 1023)];
        }
        __syncthreads();
        if (t < 16) szs[t] = np_pairwise_sumsq(&zl[t * 258]);
        __syncthreads();

        unsigned int slot = base + g;
        int k = (slot < C) ? cands[slot * 16 + j] : -1;
        int ka = (k < 0) ? 0 : k;
        const float* zrow = &zl[g * 258];
        const float4* er4 = (const float4*)(E + (size_t)ka * 256);
        float dot = 0.f;
        float4 eA[4], eB[4];
#define LOADG(buf, g_)                                                         \
    { _Pragma("unroll") for (int u = 0; u < 4; u++) buf[u] = er4[(g_) * 4 + u]; }
#define DOTG(buf, g_)                                                          \
    {                                                                          \
        _Pragma("unroll")                                                      \
        for (int u = 0; u < 4; u++) {                                          \
            int c = (g_) * 16 + u * 4;                                         \
            dot = __fmaf_rn(zrow[c + 0], buf[u].x, dot);                       \
            dot = __fmaf_rn(zrow[c + 1], buf[u].y, dot);                       \
            dot = __fmaf_rn(zrow[c + 2], buf[u].z, dot);                       \
            dot = __fmaf_rn(zrow[c + 3], buf[u].w, dot);                       \
        }                                                                      \
    }
        LOADG(eA, 0)
        LOADG(eB, 1)  DOTG(eA, 0)
        LOADG(eA, 2)  DOTG(eB, 1)
        LOADG(eB, 3)  DOTG(eA, 2)
        LOADG(eA, 4)  DOTG(eB, 3)
        LOADG(eB, 5)  DOTG(eA, 4)
        LOADG(eA, 6)  DOTG(eB, 5)
        LOADG(eB, 7)  DOTG(eA, 6)
        LOADG(eA, 8)  DOTG(eB, 7)
        LOADG(eB, 9)  DOTG(eA, 8)
        LOADG(eA, 10) DOTG(eB, 9)
        LOADG(eB, 11) DOTG(eA, 10)
        LOADG(eA, 12) DOTG(eB, 11)
        LOADG(eB, 13) DOTG(eA, 12)
        LOADG(eA, 14) DOTG(eB, 13)
        LOADG(eB, 15) DOTG(eA, 14)
        DOTG(eB, 15)
#undef LOADG
#undef DOTG
        float dmy = 3.4e38f; int ky = 0x7fffffff;
        if (k >= 0) {
            dmy = __fsub_rn(__fadd_rn(szs[g], Se[k]), __fmul_rn(2.f, dot));
            ky = k;
        }
        #pragma unroll
        for (int mask = 1; mask < 16; mask <<= 1) {
            float od = __shfl_xor(dmy, mask);
            int   ok = __shfl_xor(ky, mask);
            if (od < dmy || (od == dmy && ok < ky)) { dmy = od; ky = ok; }
        }
        if (j == 0 && slot < C) idx_out[rid[g]] = ky;
    }
}

// ---------------- kernel 3: LDS-staged full np-exact refine ----------------
__global__ __launch_bounds__(256) void refine_full(const float* __restrict__ Z,
                                                   const float* __restrict__ E,
                                                   const float* __restrict__ Se,
                                                   const unsigned int* __restrict__ cnt,
                                                   const int* __restrict__ list,
                                                   int* __restrict__ idx_out) {
    __shared__ float zl[16 * 258];
    __shared__ float els[32 * 258];
    __shared__ float szs[16];
    __shared__ int rowid[16];
    unsigned int C = *cnt;
    if (C > FULL_CAP) C = FULL_CAP;
    const int t = threadIdx.x;
    const int kk = t & 31, rr = t >> 5;
    for (unsigned int base = blockIdx.x * 16; base < C; base += gridDim.x * 16) {
        int nrows = min(16, (int)(C - base));
        __syncthreads();
        if (t < 16) rowid[t] = list[base + (t < nrows ? t : 0)];
        __syncthreads();
        for (int i = 0; i < 16; i++) {
            int n = rowid[i];
            zl[i * 258 + t] = Z[(size_t)(n >> 10) * 262144 + t * 1024 + (n & 1023)];
        }
        __syncthreads();
        if (t < 16) szs[t] = np_pairwise_sumsq(&zl[t * 258]);

        float bd0 = 3.4e38f, bd1 = 3.4e38f; int bk0 = 0x7fffffff, bk1 = 0x7fffffff;
        for (int tile = 0; tile < 32; tile++) {
            __syncthreads();
            #pragma unroll
            for (int i = 0; i < 8; i++) {
                int chunk = i * 256 + t;
                int row = chunk >> 6, x = chunk & 63;
                float4 v = *(const float4*)(E + (tile * 32 + row) * 256 + x * 4);
                float* d = &els[row * 258 + x * 4];
                d[0] = v.x; d[1] = v.y; d[2] = v.z; d[3] = v.w;
            }
            __syncthreads();
            int k = tile * 32 + kk;
            const float* e  = &els[kk * 258];
            const float* za = &zl[rr * 258];
            const float* zb = &zl[(rr + 8) * 258];
            float a0 = 0.f, a1 = 0.f;
            for (int c = 0; c < 256; c += 2) {
                float2 e2 = *(const float2*)(e + c);
                float2 x2 = *(const float2*)(za + c);
                float2 y2 = *(const float2*)(zb + c);
                a0 = __fmaf_rn(x2.x, e2.x, a0); a0 = __fmaf_rn(x2.y, e2.y, a0);
                a1 = __fmaf_rn(y2.x, e2.x, a1); a1 = __fmaf_rn(y2.y, e2.y, a1);
            }
            float sek = Se[k];
            float d0 = __fsub_rn(__fadd_rn(szs[rr], sek),     __fmul_rn(2.f, a0));
            float d1 = __fsub_rn(__fadd_rn(szs[rr + 8], sek), __fmul_rn(2.f, a1));
            if (d0 < bd0) { bd0 = d0; bk0 = k; }
            if (d1 < bd1) { bd1 = d1; bk1 = k; }
        }
        #pragma unroll
        for (int mask = 1; mask < 32; mask <<= 1) {
            float od = __shfl_xor(bd0, mask); int ok = __shfl_xor(bk0, mask);
            if (od < bd0 || (od == bd0 && ok < bk0)) { bd0 = od; bk0 = ok; }
            od = __shfl_xor(bd1, mask); ok = __shfl_xor(bk1, mask);
            if (od < bd1 || (od == bd1 && ok < bk1)) { bd1 = od; bk1 = ok; }
        }
        if (kk == 0) {
            if (rr < nrows) idx_out[rowid[rr]] = bk0;
            if (rr + 8 < nrows) idx_out[rowid[rr + 8]] = bk1;
        }
    }
}

// ---------------- kernel 4: gather z_q (f32 out), fused loss (R10-validated) ----------------
__global__ __launch_bounds__(256) void gather_loss(const float* __restrict__ Z,
                                                   const float* __restrict__ E,
                                                   const int* __restrict__ idx,
                                                   float* __restrict__ out,
                                                   float* __restrict__ loss) {
    __shared__ int nl[1024];
    __shared__ float Ecol[1024 * 9];   // 36KB
    __shared__ float rs[256];
    const int t = threadIdx.x;
    const int blk = blockIdx.x;
    const int e0 = blk * 8192;
    const int b = blk >> 5;
    const int c0 = (blk & 31) * 8;     // (e0>>10)&255
    #pragma unroll
    for (int i = 0; i < 4; i++) nl[t + i * 256] = idx[b * 1024 + t + i * 256];
    #pragma unroll
    for (int i = 0; i < 4; i++) {
        int k = i * 256 + t;
        const float4* src = (const float4*)(E + k * 256 + c0);
        float4 v0 = src[0], v1 = src[1];
        float* d = &Ecol[k * 9];
        d[0] = v0.x; d[1] = v0.y; d[2] = v0.z; d[3] = v0.w;
        d[4] = v1.x; d[5] = v1.y; d[6] = v1.z; d[7] = v1.w;
    }
    __syncthreads();
    float ls = 0.f;
    #pragma unroll 4
    for (int i = 0; i < 32; i++) {
        int off = i * 256 + t;
        int hw = off & 1023;
        int coff = off >> 10;          // 0..7
        float q = Ecol[nl[hw] * 9 + coff];
        int e = e0 + off;
        out[e] = q;
        float d = q - Z[e];
        ls += d * d;
    }
    rs[t] = ls; __syncthreads();
    for (int s = 128; s > 0; s >>= 1) { if (t < s) rs[t] += rs[t + s]; __syncthreads(); }
    if (t == 0) atomicAdd(loss, rs[0]);
}

// ---------------- kernel 5: finalize loss + indices i32 -> float in place ----------------
__global__ __launch_bounds__(256) void finalize(const float* __restrict__ loss,
                                                float* __restrict__ out) {
    int g = blockIdx.x * 256 + threadIdx.x;
    if (g == 0) out[16777216] = 1.25f * (*loss) / 16777216.f;
    int raw = ((const int*)(out + IDX_OFF))[g];
    out[IDX_OFF + g] = b2f(f2b((float)raw));  // bf16 round-trip matches bf16-cast ref
}

extern "C" void kernel_launch(void* const* d_in, const int* in_sizes, int n_in,
                              void* d_out, int out_size, void* d_ws, size_t ws_size,
                              hipStream_t stream) {
    const float* Z = (const float*)d_in[0];
    const float* E = (const float*)d_in[1];
    float* out = (float*)d_out;
    char* ws = (char*)d_ws;
    float*        loss = (float*)ws;
    unsigned int* cntF = (unsigned int*)(ws + 4);
    unsigned int* cntE = (unsigned int*)(ws + 8);
    float*        Se   = (float*)(ws + 64);
    int*          list = (int*)(ws + 4352);
    int*          idx  = (int*)(out + IDX_OFF);
    // staging in the z_q output region (all consumed before gather_loss):
    unsigned short* Ebf   = (unsigned short*)out;              // 512KB
    int*            evRow = (int*)(out + 262144);              // 256KB at +1MB
    int*            evCnd = (int*)(out + 327680);              // 4MB at +1.25MB
    unsigned short* Zbf   = (unsigned short*)(out + 2097152);  // 32MB at +8MB

    hipMemsetAsync(ws, 0, 12, stream);
    convert_e<<<128, 256, 0, stream>>>(E, Ebf, Se);
    convert_z<<<1024, 256, 0, stream>>>(Z, Zbf);
    gemm_argmin<<<1024, 256, 0, stream>>>(Zbf, Ebf, Se, idx, list, cntF, evRow, evCnd, cntE);
    eval_ambig<<<512, 256, 0, stream>>>(Z, E, Se, cntE, evRow, evCnd, idx);
    refine_full<<<256, 256, 0, stream>>>(Z, E, Se, cntF, list, idx);
    gather_loss<<<2048, 256, 0, stream>>>(Z, E, idx, out, loss);
    finalize<<<256, 256, 0, stream>>>(loss, out);
}